// Round 9
// baseline (75.919 us; speedup 1.0000x reference)
//
#include <hip/hip_runtime.h>
#include <hip/hip_cooperative_groups.h>
#include <math.h>

namespace cg = cooperative_groups;

// CapsuleLayer dynamic routing, MI355X — R9: cooperative single dispatch
// with occupancy gate + checked fallback to the proven 6-dispatch path.
// B=128, R=4096, IN=16, OUT=32, C=2, 3 routing iterations.
//
// Math structure (R5-R7, proven): priors never materialized; logits are
// linear in the running v-sum, so all 3 iterations run the same pass body:
//   p = x.W per row via mfma_f32_16x16x32_f16 (A=W^T frag m=o, B=x frag n=b)
//   e = exp(p . vsum)   [it0: e=1, uniform softmax]
//   acc += e*p, esum += e -> chunk partials -> redv (squash, vsum update).
// R9 changes vs R8 (which failed: coop launch silently errored, kernel
// never ran — 36.9 KB LDS -> 1 block/CU under a 64 KB budget -> 512-block
// coop grid rejected):
//   * LDS shrunk to exactly 32768 B (2-half W stage; no OutL transpose:
//     fragments stored DIRECTLY to partialA, redv un-permutes via idx calc).
//   * hipOccupancyMaxActiveBlocksPerMultiprocessor gate (>=2 blocks/CU)
//     before attempting coop; coop return code checked; full fallback path.
// k-slot safety (HW-verified R6/R7): both mfma operands put i=4*(L>>4)+j in
// elements 0..3, zeros in 4..7. C/D layout (m89): col=lane&15, row=4*(g)+reg.
#define CB    128
#define CR    4096
#define CIN   16
#define COUT  32
#define CCAP  2
#define RC    16            // r rows per pass block
#define NRCH  (CR / RC)     // 256 chunks per c
#define GRID  (CCAP * NRCH) // 512 blocks
#define EPSF  1e-12f

typedef _Float16 h8  __attribute__((ext_vector_type(8)));
typedef _Float16 h4t __attribute__((ext_vector_type(4)));
typedef float    f4  __attribute__((ext_vector_type(4)));

// ---------------------------------------------------------------------------
// stage W rows [r0, r0+16) f32 -> packed f16 fragment order in WpL (16 KB),
// using a 16 KB scratch (Stg) in two 8-row halves. 4 barriers, startup only.
// Fragment layout (R6-verified): WpL_h4[ri*128 + ot*64 + L][j] =
//   (f16) W[c][r0+ri][4*(L>>4)+j][ot*16 + (L&15)]
// ---------------------------------------------------------------------------
__device__ __forceinline__ void stage_pack_W(const float* __restrict__ w,
                                             int c, int r0, int t,
                                             _Float16* WpL, float* Stg)
{
  h4t* WpL4 = (h4t*)WpL;
#pragma unroll
  for (int h = 0; h < 2; ++h) {
    const float4* src = (const float4*)(w + ((size_t)c * CR + r0 + h * 8) * 512);
    ((float4*)Stg)[t]       = src[t];
    ((float4*)Stg)[t + 512] = src[t + 512];
    __syncthreads();
#pragma unroll
    for (int q = 0; q < 2; ++q) {
      const int sl  = t * 2 + q;         // 0..1023
      const int rr  = sl >> 7;           // row within half
      const int rem = sl & 127;          // ot*64 + L
      const int ot  = rem >> 6;
      const int gs  = (rem >> 4) & 3;
      const int ms  = rem & 15;
      h4t v;
#pragma unroll
      for (int j = 0; j < 4; ++j)
        v[j] = (_Float16)Stg[rr * 512 + (4 * gs + j) * 32 + ot * 16 + ms];
      WpL4[(h * 8 + rr) * 128 + rem] = v;
    }
    __syncthreads();
  }
}

// ---------------------------------------------------------------------------
// pass body: 512 threads = 8 waves (b-tiles of 16). Per r: 2 mfma ->
// P[o][b] frags; d = P.v (8 FMA + 2 shfl_xor); e = exp(d); acc += e*P.
// Epilogue: direct fragment-order stores (coalesced t*8), NO barriers.
// partialA record per (c,rch): 4096 floats; element (b,o) at
//   idx = (wv*64 + g*16 + m)*8 + (o>>4)*4 + (o&3),  g=(o&15)>>2.
// ---------------------------------------------------------------------------
__device__ __forceinline__ void pass_body(const float* __restrict__ x,
                                          const float* __restrict__ vsum,
                                          float* __restrict__ partialA,
                                          float* __restrict__ partialE,
                                          const _Float16* WpL,
                                          int c, int rch, int t, int uniform)
{
  const int r0 = rch * RC;
  const int wv = t >> 6, L = t & 63, g = L >> 4, m = L & 15;
  const int b  = wv * 16 + m;
  const h4t* WpL4 = (const h4t*)WpL;

  float4 vA = {0.f, 0.f, 0.f, 0.f}, vB = {0.f, 0.f, 0.f, 0.f};
  if (!uniform) {
    const float* vb = vsum + ((size_t)c * CB + b) * COUT;
    vA = *(const float4*)(vb + 4 * g);
    vB = *(const float4*)(vb + 16 + 4 * g);
  }
  float accA[4] = {0.f, 0.f, 0.f, 0.f};
  float accB[4] = {0.f, 0.f, 0.f, 0.f};
  float esum = 0.f;

#pragma unroll 4
  for (int ri = 0; ri < RC; ++ri) {
    const int r = r0 + ri;
    // B-frag: x[b][r][4g..4g+3] -> elements 0..3, zeros 4..7
    float4 xf = *(const float4*)(x + ((size_t)b * CR + r) * CIN + 4 * g);
    h8 bx = {(_Float16)xf.x, (_Float16)xf.y, (_Float16)xf.z, (_Float16)xf.w,
             (_Float16)0.f, (_Float16)0.f, (_Float16)0.f, (_Float16)0.f};
    h4t wA4 = WpL4[ri * 128 + L];
    h4t wB4 = WpL4[ri * 128 + 64 + L];
    h8 aA = {wA4[0], wA4[1], wA4[2], wA4[3],
             (_Float16)0.f, (_Float16)0.f, (_Float16)0.f, (_Float16)0.f};
    h8 aB = {wB4[0], wB4[1], wB4[2], wB4[3],
             (_Float16)0.f, (_Float16)0.f, (_Float16)0.f, (_Float16)0.f};
    f4 z = {0.f, 0.f, 0.f, 0.f};
    f4 pA = __builtin_amdgcn_mfma_f32_16x16x32_f16(aA, bx, z, 0, 0, 0);
    f4 pB = __builtin_amdgcn_mfma_f32_16x16x32_f16(aB, bx, z, 0, 0, 0);

    float e = 1.f;                 // it0: softmax over zero logits
    if (!uniform) {
      float d = pA[0] * vA.x + pA[1] * vA.y + pA[2] * vA.z + pA[3] * vA.w
              + pB[0] * vB.x + pB[1] * vB.y + pB[2] * vB.z + pB[3] * vB.w;
      d += __shfl_xor(d, 16);
      d += __shfl_xor(d, 32);
      e = __expf(d);
    }
    esum += e;
#pragma unroll
    for (int j = 0; j < 4; ++j) { accA[j] += e * pA[j]; accB[j] += e * pB[j]; }
  }

  float4 a4 = {accA[0], accA[1], accA[2], accA[3]};
  float4 b4 = {accB[0], accB[1], accB[2], accB[3]};
  float* dst = partialA + ((size_t)(c * NRCH + rch)) * 4096 + (size_t)t * 8;
  *(float4*)dst = a4;
  *(float4*)(dst + 4) = b4;
  if (g == 0) partialE[((size_t)(c * NRCH + rch)) * CB + b] = esum;   // e same across g
}

// ---------------------------------------------------------------------------
// redv body: per (c,b) reduce NRCH chunk-partials (fragment-order, via idx
// permutation) -> v = squash(s/esum). mode: 0 vsum=v, 1 vsum+=v, 2 out=v.
// JG = thread count / 32 (chunk groups).
// ---------------------------------------------------------------------------
template <int JG>
__device__ __forceinline__ void redv_body(const float* __restrict__ partialA,
                                          const float* __restrict__ partialE,
                                          float* __restrict__ vsum,
                                          float* __restrict__ out,
                                          float (*red)[33], float* rede,
                                          int cb, int t, int mode)
{
  const int c2 = cb >> 7, b2 = cb & 127;
  const int o = t & 31, jg = t >> 5;
  const int wv2 = b2 >> 4, m2 = b2 & 15;
  const int half = o >> 4, oo = o & 15, g2 = oo >> 2, j2 = oo & 3;
  const size_t idx = (size_t)(wv2 * 64 + g2 * 16 + m2) * 8 + half * 4 + j2;

  float s = 0.f;
#pragma unroll 4
  for (int k = 0; k < NRCH / JG; ++k) {
    const int j = jg + k * JG;
    s += partialA[((size_t)(c2 * NRCH + j)) * 4096 + idx];
  }
  red[jg][o] = s;
  __syncthreads();

  if (t < JG) {
    float e = 0.f;
#pragma unroll 4
    for (int k = 0; k < NRCH / JG; ++k)
      e += partialE[((size_t)(c2 * NRCH + t + k * JG)) * CB + b2];
    rede[t] = e;
  }
  __syncthreads();

  if (t < 32) {
    float sv = 0.f, es = 0.f;
#pragma unroll
    for (int jj = 0; jj < JG; ++jj) { sv += red[jj][t]; es += rede[jj]; }
    float sm = sv / es;
    float sn = sm * sm;
#pragma unroll
    for (int sh = 1; sh < 32; sh <<= 1) sn += __shfl_xor(sn, sh);
    float fac = sn / ((1.f + sn + EPSF) * sqrtf(sn + EPSF));
    float vv = sm * fac;
    if (mode == 2)      out[cb * COUT + t]  = vv;
    else if (mode == 1) vsum[cb * COUT + t] += vv;
    else                vsum[cb * COUT + t] = vv;
  }
}

// ---------------------------------------------------------------------------
// cooperative fused kernel: 512 blocks x 512 threads, LDS exactly 32768 B
// -> 2 blocks/CU even under a 64 KB LDS budget. W staged+packed ONCE.
// ---------------------------------------------------------------------------
__global__ __launch_bounds__(512, 4) void caps_coop_kernel(
    const float* __restrict__ x, const float* __restrict__ w,
    float* __restrict__ vsum, float* __restrict__ partialA,
    float* __restrict__ partialE, float* __restrict__ out)
{
  cg::grid_group grid = cg::this_grid();
  const int blk = (int)blockIdx.x;
  const int c = blk >> 8, rch = blk & 255;
  const int t = (int)threadIdx.x;

  __shared__ __align__(16) char lds[32768];
  _Float16* WpL = (_Float16*)lds;                       // [0,16384) persistent
  float* Stg = (float*)(lds + 16384);                   // [16384,32768) scratch
  float (*red)[33] = (float (*)[33])(lds + 16384);      // redv scratch (aliases Stg)
  float* rede = (float*)(lds + 16384 + 16 * 33 * 4);

  stage_pack_W(w, c, rch * RC, t, WpL, Stg);

#pragma unroll 1
  for (int it = 0; it < 3; ++it) {
    pass_body(x, vsum, partialA, partialE, WpL, c, rch, t, it == 0);
    __threadfence();
    grid.sync();
    if (blk < 256)
      redv_body<16>(partialA, partialE, vsum, out, red, rede, blk, t, it);
    if (it < 2) {
      __threadfence();
      grid.sync();
    }
  }
}

// ---------------------------------------------------------------------------
// fallback kernels (6-dispatch path, proven R7 structure + R9 improvements)
// ---------------------------------------------------------------------------
__global__ __launch_bounds__(512) void caps_pass_kernel(
    const float* __restrict__ x, const float* __restrict__ w,
    const float* __restrict__ vsum, float* __restrict__ partialA,
    float* __restrict__ partialE, int uniform)
{
  const int blk = (int)blockIdx.x;
  const int c = blk >> 8, rch = blk & 255;
  const int t = (int)threadIdx.x;
  __shared__ __align__(16) char lds[32768];
  _Float16* WpL = (_Float16*)lds;
  float* Stg = (float*)(lds + 16384);
  stage_pack_W(w, c, rch * RC, t, WpL, Stg);
  pass_body(x, vsum, partialA, partialE, WpL, c, rch, t, uniform);
}

__global__ __launch_bounds__(256) void caps_redv_kernel(
    const float* __restrict__ partialA, const float* __restrict__ partialE,
    float* __restrict__ vsum, float* __restrict__ out, int mode)
{
  __shared__ float red[8][33];
  __shared__ float rede[8];
  redv_body<8>(partialA, partialE, vsum, out, red, rede,
               (int)blockIdx.x, (int)threadIdx.x, mode);
}

extern "C" void kernel_launch(void* const* d_in, const int* in_sizes, int n_in,
                              void* d_out, int out_size, void* d_ws, size_t ws_size,
                              hipStream_t stream) {
  const float* x = (const float*)d_in[0];
  const float* w = (const float*)d_in[1];
  float* out = (float*)d_out;

  char* p = (char*)d_ws;
  float* vsum = (float*)p;                         // 32,768 B
  p += (size_t)CCAP * CB * COUT * sizeof(float);
  float* partialA = (float*)p;                     // 2*256*4096*4 = 8,388,608 B
  p += (size_t)CCAP * NRCH * 4096 * sizeof(float);
  float* partialE = (float*)p;                     // 262,144 B

  // Occupancy gate (pure host query, deterministic, capture-safe): only
  // attempt cooperative launch if >=2 blocks/CU fit -> 512 co-resident.
  int maxB = 0;
  bool coop_ok =
      (hipOccupancyMaxActiveBlocksPerMultiprocessor(
           &maxB, (const void*)caps_coop_kernel, 512, 0) == hipSuccess) &&
      (maxB >= 2);

  if (coop_ok) {
    void* args[] = {(void*)&x, (void*)&w, (void*)&vsum,
                    (void*)&partialA, (void*)&partialE, (void*)&out};
    hipError_t e = hipLaunchCooperativeKernel((const void*)caps_coop_kernel,
                                              dim3(GRID), dim3(512), args, 0,
                                              stream);
    if (e == hipSuccess) return;
    (void)hipGetLastError();   // clear sticky error, fall through
  }

  // fallback: proven 6-dispatch path
  for (int it = 0; it < 3; ++it) {
    caps_pass_kernel<<<dim3(GRID), 512, 0, stream>>>(
        x, w, vsum, partialA, partialE, it == 0 ? 1 : 0);
    caps_redv_kernel<<<dim3(CCAP * CB), 256, 0, stream>>>(
        partialA, partialE, vsum, out, it);
  }
}